// Round 5
// baseline (58.782 us; speedup 1.0000x reference)
//
#include <hip/hip_runtime.h>

#define NSEG 4096

__device__ __forceinline__ void acc4(float4& a, const float4 v) {
    a.x += v.x; a.y += v.y; a.z += v.z; a.w += v.w;
}

// ---------- K0: setup — bounds[s] = lower_bound(seg, s) AND Wt = W^T ----------
__global__ __launch_bounds__(256) void setup_kernel(
    const int*   __restrict__ seg,    // [nrows] sorted
    const float* __restrict__ W,      // [32][512]
    int*         __restrict__ bounds, // [NSEG+1]
    float*       __restrict__ Wt,     // [512][32]
    int nrows)
{
    const int i = blockIdx.x * 256 + threadIdx.x;
    if (i < 512 * 32) {
        const int d = i >> 5, j = i & 31;
        Wt[i] = W[j * 512 + d];
    }
    if (i >= nrows) return;
    const int cur  = seg[i];
    const int prev = (i == 0) ? -1 : seg[i - 1];
    for (int s = prev + 1; s <= cur; ++s) bounds[s] = i;
    if (i == nrows - 1) {
        for (int s = cur + 1; s <= NSEG; ++s) bounds[s] = nrows;
    }
}

// ---------- K1: pure-streaming mean-pool ----------
// 2048 blocks x 256 thr = 8192 waves = exactly 32 waves/CU, ONE generation.
// Wave w of block b owns (segment 2b + (w>>1), emb half w&1) — fully
// independent: no LDS, no barriers, no shuffles. Unroll-8 row loop.
__global__ __launch_bounds__(256, 8) void pool_kernel(
    const float* __restrict__ emb_a,
    const float* __restrict__ emb_b,
    const int*   __restrict__ bounds,  // [NSEG+1]
    float*       __restrict__ pooled)  // [NSEG][512]
{
    const int t    = threadIdx.x;
    const int wave = t >> 6;
    const int lane = t & 63;
    const int s    = (blockIdx.x << 1) + (wave >> 1);

    const int start = bounds[s];
    const int end   = bounds[s + 1];
    const int cnt   = end - start;

    const float*  base = (wave & 1) ? emb_b : emb_a;
    const float4* src  = reinterpret_cast<const float4*>(base) + lane; // row stride 64 float4

    float4 a0{0,0,0,0}, a1{0,0,0,0}, a2{0,0,0,0}, a3{0,0,0,0};

    int r = start;
    for (; r + 8 <= end; r += 8) {
        float4 v0 = src[(size_t)(r+0)*64];
        float4 v1 = src[(size_t)(r+1)*64];
        float4 v2 = src[(size_t)(r+2)*64];
        float4 v3 = src[(size_t)(r+3)*64];
        float4 v4 = src[(size_t)(r+4)*64];
        float4 v5 = src[(size_t)(r+5)*64];
        float4 v6 = src[(size_t)(r+6)*64];
        float4 v7 = src[(size_t)(r+7)*64];
        acc4(a0, v0); acc4(a1, v1); acc4(a2, v2); acc4(a3, v3);
        acc4(a0, v4); acc4(a1, v5); acc4(a2, v6); acc4(a3, v7);
    }
    for (; r + 4 <= end; r += 4) {
        float4 v0 = src[(size_t)(r+0)*64];
        float4 v1 = src[(size_t)(r+1)*64];
        float4 v2 = src[(size_t)(r+2)*64];
        float4 v3 = src[(size_t)(r+3)*64];
        acc4(a0, v0); acc4(a1, v1); acc4(a2, v2); acc4(a3, v3);
    }
    for (; r < end; ++r) acc4(a0, src[(size_t)r * 64]);

    const float inv = 1.0f / (float)max(cnt, 1);
    float4 acc;
    acc.x = (a0.x + a1.x + a2.x + a3.x) * inv;
    acc.y = (a0.y + a1.y + a2.y + a3.y) * inv;
    acc.z = (a0.z + a1.z + a2.z + a3.z) * inv;
    acc.w = (a0.w + a1.w + a2.w + a3.w) * inv;

    *reinterpret_cast<float4*>(pooled + (size_t)s * 512 + ((wave & 1) << 8) + (lane << 2)) = acc;
}

// ---------- K2: pooled[4096,512] @ Wt[512,32] + b -> out[4096,32] ----------
// 256 blocks x 128 thr. Thread = (seg = bid*16 + t>>3, j4 = t&7) computes 4
// outputs out[seg][4*j4 .. +4). Wt rows read contiguously (128 B/wave-instr),
// P rows L1-resident (32 KB/block). All float4, no LDS, no reductions.
__global__ __launch_bounds__(128) void proj_kernel(
    const float* __restrict__ pooled,  // [NSEG][512]
    const float* __restrict__ Wt,      // [512][32]
    const float* __restrict__ bias,    // [32]
    float*       __restrict__ out)     // [NSEG][32]
{
    const int t   = threadIdx.x;
    const int seg = blockIdx.x * 16 + (t >> 3);
    const int j4  = t & 7;

    const float4* P  = reinterpret_cast<const float4*>(pooled + (size_t)seg * 512);
    const float4* WT = reinterpret_cast<const float4*>(Wt) + j4;  // row d: 8 float4s

    float4 acc{0,0,0,0};
    #pragma unroll 4
    for (int d4 = 0; d4 < 128; ++d4) {
        const float4 p  = P[d4];
        const float4 w0 = WT[(size_t)(4*d4 + 0) * 8];
        const float4 w1 = WT[(size_t)(4*d4 + 1) * 8];
        const float4 w2 = WT[(size_t)(4*d4 + 2) * 8];
        const float4 w3 = WT[(size_t)(4*d4 + 3) * 8];
        acc.x += p.x*w0.x + p.y*w1.x + p.z*w2.x + p.w*w3.x;
        acc.y += p.x*w0.y + p.y*w1.y + p.z*w2.y + p.w*w3.y;
        acc.z += p.x*w0.z + p.y*w1.z + p.z*w2.z + p.w*w3.z;
        acc.w += p.x*w0.w + p.y*w1.w + p.z*w2.w + p.w*w3.w;
    }
    const float4 bb = reinterpret_cast<const float4*>(bias)[j4];
    float4 o;
    o.x = acc.x + bb.x; o.y = acc.y + bb.y;
    o.z = acc.z + bb.z; o.w = acc.w + bb.w;
    reinterpret_cast<float4*>(out + (size_t)seg * 32)[j4] = o;
}

// ---------- Fallback (ws too small): self-contained fused kernel ----------
__global__ __launch_bounds__(128, 8) void fused_fallback_kernel(
    const float* __restrict__ emb_a,
    const float* __restrict__ emb_b,
    const int*   __restrict__ seg,
    const float* __restrict__ W,
    const float* __restrict__ bias,
    float*       __restrict__ out,
    int nrows)
{
    const int s = blockIdx.x;
    const int t = threadIdx.x;
    const int wave = t >> 6;
    const int lane = t & 63;
    __shared__ int   bnd[2];
    __shared__ float pooled[512];
    __shared__ float sh_out[32];
    if (t < 2) {
        int target = s + t;
        int lo = 0, hi = nrows;
        while (lo < hi) { int mid = (lo + hi) >> 1; if (seg[mid] < target) lo = mid + 1; else hi = mid; }
        bnd[t] = lo;
    }
    __syncthreads();
    const int start = bnd[0], end = bnd[1];
    const int cnt = end - start;
    const float*  base = (wave == 0) ? emb_a : emb_b;
    const float4* src  = reinterpret_cast<const float4*>(base) + lane;
    float4 a0{0,0,0,0}, a1{0,0,0,0}, a2{0,0,0,0}, a3{0,0,0,0};
    int r = start;
    for (; r + 4 <= end; r += 4) {
        float4 v0 = src[(size_t)(r+0)*64];
        float4 v1 = src[(size_t)(r+1)*64];
        float4 v2 = src[(size_t)(r+2)*64];
        float4 v3 = src[(size_t)(r+3)*64];
        acc4(a0, v0); acc4(a1, v1); acc4(a2, v2); acc4(a3, v3);
    }
    for (; r < end; ++r) acc4(a0, src[(size_t)r * 64]);
    const float inv = 1.0f / (float)max(cnt, 1);
    float4 acc;
    acc.x = (a0.x + a1.x + a2.x + a3.x) * inv;
    acc.y = (a0.y + a1.y + a2.y + a3.y) * inv;
    acc.z = (a0.z + a1.z + a2.z + a3.z) * inv;
    acc.w = (a0.w + a1.w + a2.w + a3.w) * inv;
    *reinterpret_cast<float4*>(pooled + (wave << 8) + (lane << 2)) = acc;
    __syncthreads();
    const float4* pool4 = reinterpret_cast<const float4*>(pooled);
    const float4  p0 = pool4[lane];
    const float4  p1 = pool4[64 + lane];
    #pragma unroll 4
    for (int jj = 0; jj < 16; ++jj) {
        const int j = (wave << 4) + jj;
        const float4* wrow = reinterpret_cast<const float4*>(W + j * 512);
        const float4  w0 = wrow[lane];
        const float4  w1 = wrow[64 + lane];
        float v = p0.x*w0.x + p0.y*w0.y + p0.z*w0.z + p0.w*w0.w
                + p1.x*w1.x + p1.y*w1.y + p1.z*w1.z + p1.w*w1.w;
        v += __shfl_xor(v, 1);
        v += __shfl_xor(v, 2);
        v += __shfl_xor(v, 4);
        v += __shfl_xor(v, 8);
        v += __shfl_xor(v, 16);
        v += __shfl_xor(v, 32);
        if (lane == 0) sh_out[j] = v + bias[j];
    }
    __syncthreads();
    if (t < 32) out[s * 32 + t] = sh_out[t];
}

extern "C" void kernel_launch(void* const* d_in, const int* in_sizes, int n_in,
                              void* d_out, int out_size, void* d_ws, size_t ws_size,
                              hipStream_t stream) {
    const float* emb_a = (const float*)d_in[0];
    const float* emb_b = (const float*)d_in[1];
    const int*   seg   = (const int*)d_in[2];
    const float* W     = (const float*)d_in[3];
    const float* bias  = (const float*)d_in[4];
    float*       out   = (float*)d_out;
    const int nrows = in_sizes[2];

    // ws layout: bounds @ 0 (4097 ints), Wt @ 32768 (64 KB), pooled @ 98304 (8 MB)
    const size_t OFF_WT     = 32768;
    const size_t OFF_POOLED = 98304;
    const size_t need       = OFF_POOLED + (size_t)NSEG * 512 * sizeof(float);

    if (ws_size >= need) {
        int*   bounds = (int*)d_ws;
        float* Wt     = (float*)((char*)d_ws + OFF_WT);
        float* pooled = (float*)((char*)d_ws + OFF_POOLED);
        setup_kernel<<<(nrows + 255) / 256, 256, 0, stream>>>(seg, W, bounds, Wt, nrows);
        pool_kernel<<<NSEG / 2, 256, 0, stream>>>(emb_a, emb_b, bounds, pooled);
        proj_kernel<<<NSEG / 16, 128, 0, stream>>>(pooled, Wt, bias, out);
    } else {
        fused_fallback_kernel<<<NSEG, 128, 0, stream>>>(emb_a, emb_b, seg, W, bias, out, nrows);
    }
}